// Round 1
// baseline (911.080 us; speedup 1.0000x reference)
//
#include <hip/hip_runtime.h>

// MACE body-3 interaction, fused per-atom kernel, fp32.
// N=1024 atoms, M=9 irreps rows, C=64 channels, P3=16, P2=4, P1=2.
// One block per atom, 256 threads. All intermediates in LDS/registers.

__global__ __launch_bounds__(256, 4) void mace_b3(
    const float* __restrict__ irreps_x,   // [N][9][64]
    const int*   __restrict__ atomic_numbers, // [N]
    const float* __restrict__ w_fc1,      // [3][64][64]
    const float* __restrict__ b_fc1,      // [64]
    const float* __restrict__ U3,         // [9][9][9][9][16]
    const float* __restrict__ W3,         // [E][16][64]
    const float* __restrict__ U2,         // [9][9][9][4]
    const float* __restrict__ W2,         // [E][4][64]
    const float* __restrict__ U1,         // [9][9][2]
    const float* __restrict__ W1,         // [E][2][64]
    const float* __restrict__ w_lin,      // [3][64][64]
    const float* __restrict__ w_fc2,      // [3][64][64]
    const float* __restrict__ b_fc2,      // [64]
    float* __restrict__ out)              // [N][9][64]
{
    // LDS layout (floats), hand-aliased to stay at 40320B -> 4 blocks/CU:
    __shared__ float smem[10080];
    float* const xin   = smem;          // 576   (dead after phase A)
    float* const xv    = smem + 576;    // 576   (live throughout)
    float* const s3    = smem + 1152;   // 4608  [ip=144][c=32]
    float* const s2    = smem + 5760;   // 1152  [ip2=36][c=32]
    float* const s1    = smem + 6912;   // 576   [ip1=18][c=32]
    float* const out2L = smem + 7488;   // 2592  [oa=81][c=32]
    float* const mainL = smem;          // alias xin (written at out1 phase)
    float* const yL    = smem + 1152;   // alias s3 (phase C only)

    const int n = blockIdx.x;
    const int t = threadIdx.x;

    // ---- load irreps row into LDS ----
    const float* xrow = irreps_x + n * 576;
    for (int idx = t; idx < 576; idx += 256) xin[idx] = xrow[idx];
    __syncthreads();

    // ---- phase A: xv[m][d] = (m==0)*b_fc1[d] + sum_c xin[m][c]*w_fc1[l][d][c]
    for (int idx = t; idx < 576; idx += 256) {
        const int m = idx >> 6, d = idx & 63;
        const int l = (m >= 4) ? 2 : (m >= 1 ? 1 : 0);
        const float4* xr = (const float4*)(xin + m * 64);
        const float4* wr = (const float4*)(w_fc1 + l * 4096 + d * 64);
        float acc = (m == 0) ? b_fc1[d] : 0.0f;
        #pragma unroll
        for (int q = 0; q < 16; ++q) {
            const float4 a = xr[q]; const float4 w = wr[q];
            acc += a.x*w.x + a.y*w.y + a.z*w.z + a.w*w.w;
        }
        xv[idx] = acc;
    }
    __syncthreads();

    const int an = atomic_numbers[n];
    const float* W3r = W3 + an * (16 * 64);
    const float* W2r = W2 + an * (4 * 64);
    const float* W1r = W1 + an * (2 * 64);

    // ---- main tensor-product, two c-halves of 32 channels ----
    for (int h = 0; h < 2; ++h) {
        const int cbase = 32 * h;

        // fill s3[ip][c]=x_i*w3_p, s2, s1 for this half
        for (int idx = t; idx < 6336; idx += 256) {
            if (idx < 4608) {
                const int ip = idx >> 5, c = idx & 31;
                s3[idx] = xv[(ip >> 4) * 64 + cbase + c] *
                          W3r[(ip & 15) * 64 + cbase + c];
            } else if (idx < 5760) {
                const int j = idx - 4608;
                const int ip = j >> 5, c = j & 31;
                s2[j] = xv[(ip >> 2) * 64 + cbase + c] *
                        W2r[(ip & 3) * 64 + cbase + c];
            } else {
                const int j = idx - 5760;
                const int ip = j >> 5, c = j & 31;
                s1[j] = xv[(ip >> 1) * 64 + cbase + c] *
                        W1r[(ip & 1) * 64 + cbase + c];
            }
        }
        __syncthreads();

        // main: per (oa, c): T3[b] = dot144(U3 row, s3[:,c]); fold to out2
        {
            const int c  = t & 31;
            const int wv = t >> 5;                 // 0..7 (half-wave id)
            const float* s3c = s3 + c;
            const float* s2c = s2 + c;
            for (int oa = wv; oa < 81; oa += 8) {
                const float* u3p = U3 + oa * 1296; // rows oa*9 .. oa*9+8
                float acc[9];
                #pragma unroll
                for (int b = 0; b < 9; ++b) acc[b] = 0.0f;
                for (int ip4 = 0; ip4 < 36; ++ip4) {
                    const float sa = s3c[(ip4*4+0)*32];
                    const float sb = s3c[(ip4*4+1)*32];
                    const float sc = s3c[(ip4*4+2)*32];
                    const float sd = s3c[(ip4*4+3)*32];
                    #pragma unroll
                    for (int b = 0; b < 9; ++b) {
                        const float4 u = *(const float4*)(u3p + b*144 + ip4*4);
                        acc[b] += u.x*sa + u.y*sb + u.z*sc + u.w*sd;
                    }
                }
                // out2[oa] = sum_b T3[b]*x_b + sum_{i,p} U2[oa,i,p]*x_i*w2_p
                float o2 = 0.0f;
                #pragma unroll
                for (int b = 0; b < 9; ++b) o2 += acc[b] * xv[b*64 + cbase + c];
                const float4* u2p = (const float4*)(U2 + oa * 36);
                #pragma unroll
                for (int q = 0; q < 9; ++q) {
                    const float4 u = u2p[q];
                    o2 += u.x * s2c[(q*4+0)*32] + u.y * s2c[(q*4+1)*32]
                        + u.z * s2c[(q*4+2)*32] + u.w * s2c[(q*4+3)*32];
                }
                out2L[oa*32 + c] = o2;
            }
        }
        __syncthreads();

        // out1[o] = sum_a out2[o,a]*x_a + sum_{i,p} U1[o,i,p]*x_i*w1_p
        for (int idx = t; idx < 288; idx += 256) {
            const int o = idx >> 5, c = idx & 31;
            float o1 = 0.0f;
            #pragma unroll
            for (int a = 0; a < 9; ++a)
                o1 += out2L[(o*9+a)*32 + c] * xv[a*64 + cbase + c];
            #pragma unroll
            for (int q = 0; q < 18; ++q)
                o1 += U1[o*18 + q] * s1[q*32 + c];
            mainL[o*64 + cbase + c] = o1;
        }
        __syncthreads();  // protects s3/s2/s1/out2L refill in next half
    }

    // ---- phase C1: yL = so3_linear(mainL, w_lin) ----
    for (int idx = t; idx < 576; idx += 256) {
        const int m = idx >> 6, d = idx & 63;
        const int l = (m >= 4) ? 2 : (m >= 1 ? 1 : 0);
        const float4* xr = (const float4*)(mainL + m * 64);
        const float4* wr = (const float4*)(w_lin + l * 4096 + d * 64);
        float acc = 0.0f;
        #pragma unroll
        for (int q = 0; q < 16; ++q) {
            const float4 a = xr[q]; const float4 w = wr[q];
            acc += a.x*w.x + a.y*w.y + a.z*w.z + a.w*w.w;
        }
        yL[idx] = acc;
    }
    __syncthreads();

    // ---- phase C2: out = so3_linear(yL, w_fc2, b_fc2) ----
    float* orow = out + n * 576;
    for (int idx = t; idx < 576; idx += 256) {
        const int m = idx >> 6, d = idx & 63;
        const int l = (m >= 4) ? 2 : (m >= 1 ? 1 : 0);
        const float4* xr = (const float4*)(yL + m * 64);
        const float4* wr = (const float4*)(w_fc2 + l * 4096 + d * 64);
        float acc = (m == 0) ? b_fc2[d] : 0.0f;
        #pragma unroll
        for (int q = 0; q < 16; ++q) {
            const float4 a = xr[q]; const float4 w = wr[q];
            acc += a.x*w.x + a.y*w.y + a.z*w.z + a.w*w.w;
        }
        orow[idx] = acc;
    }
}

extern "C" void kernel_launch(void* const* d_in, const int* in_sizes, int n_in,
                              void* d_out, int out_size, void* d_ws, size_t ws_size,
                              hipStream_t stream) {
    const float* irreps_x = (const float*)d_in[0];
    const int*   anum     = (const int*)d_in[1];
    const float* w_fc1    = (const float*)d_in[2];
    const float* b_fc1    = (const float*)d_in[3];
    const float* U3       = (const float*)d_in[4];
    const float* W3       = (const float*)d_in[5];
    const float* U2       = (const float*)d_in[6];
    const float* W2       = (const float*)d_in[7];
    const float* U1       = (const float*)d_in[8];
    const float* W1       = (const float*)d_in[9];
    const float* w_lin    = (const float*)d_in[10];
    const float* w_fc2    = (const float*)d_in[11];
    const float* b_fc2    = (const float*)d_in[12];
    float* out = (float*)d_out;

    mace_b3<<<1024, 256, 0, stream>>>(irreps_x, anum, w_fc1, b_fc1, U3, W3,
                                      U2, W2, U1, W1, w_lin, w_fc2, b_fc2, out);
}

// Round 2
// 212.705 us; speedup vs baseline: 4.2833x; 4.2833x over previous
//
#include <hip/hip_runtime.h>

// MACE body-3, MFMA formulation.
// Per atom: out3[c][oab] = sum_ip s3[c][ip] * U3r[ip][oab]  (GEMM, bf16 MFMA)
// with N padded to oa*16+b (b<9 real, b==9 carries the U2 term, rest zero),
// K = 192 (144 U3-ip ++ 36 U2-ip ++ 12 zero). Epilogue folds sum_b (.. * x_b)
// via 16-lane shfl_xor. so3_linears done as block-diagonal K=192 MFMAs.

typedef __attribute__((ext_vector_type(8))) short short8;
typedef __attribute__((ext_vector_type(4))) float f32x4;

static __device__ __forceinline__ unsigned short f2bf(float f) {
    union { float f; unsigned u; } v; v.f = f;
    unsigned r = v.u + 0x7fffu + ((v.u >> 16) & 1u);
    return (unsigned short)(r >> 16);
}
static __device__ __forceinline__ float bf2f(unsigned short h) {
    union { unsigned u; float f; } v; v.u = ((unsigned)h) << 16;
    return v.f;
}

// ---- prep: repack U3 (+U2 into b-slot 9) into fragment-ordered bf16 ----
// U3w index: ((kt*81 + nt)*64 + lane) -> short8 (8 consecutive k for this
// lane's (b=lane&15, kgroup=lane>>4) position).  Size: 6*81*64*16B = 486 KB.
__global__ void prep_u3w(const float* __restrict__ U3, const float* __restrict__ U2,
                         unsigned short* __restrict__ U3w)
{
    int idx = blockIdx.x * 256 + threadIdx.x;
    if (idx >= 6 * 81 * 64) return;
    int l  = idx & 63;
    int nt = (idx >> 6) % 81;
    int kt = idx / (81 * 64);
    int b  = l & 15;
    int k0 = kt * 32 + (l >> 4) * 8;
    short8 pk;
    #pragma unroll
    for (int j = 0; j < 8; ++j) {
        int k = k0 + j;
        float f = 0.f;
        if (b < 9)       { if (k < 144)             f = U3[(nt * 9 + b) * 144 + k]; }
        else if (b == 9) { if (k >= 144 && k < 180) f = U2[nt * 36 + (k - 144)]; }
        pk[j] = (short)f2bf(f);
    }
    ((short8*)U3w)[idx] = pk;
}

__global__ __launch_bounds__(1024, 4) void mace_main(
    const float* __restrict__ irreps_x,
    const int*   __restrict__ atomic_numbers,
    const float* __restrict__ w_fc1,
    const float* __restrict__ b_fc1,
    const float* __restrict__ W3,
    const float* __restrict__ W2,
    const float* __restrict__ U1,
    const float* __restrict__ W1,
    const float* __restrict__ w_lin,
    const float* __restrict__ w_fc2,
    const float* __restrict__ b_fc2,
    const unsigned short* __restrict__ U3w,
    float* __restrict__ out)
{
    __shared__ __align__(16) float xvL[4 * 576];              //  9216 B
    __shared__ __align__(16) unsigned char region[102400];    // aliased
    __shared__ __align__(16) unsigned short o2L[4 * 81 * 64]; // 41472 B
    // total 153088 B -> 1 block/CU, 16 waves

    const int t  = threadIdx.x;
    const int n0 = blockIdx.x * 4;
    const int w  = t >> 6;
    const int l  = t & 63;
    const int kg = l >> 4;

    unsigned short* s3L = (unsigned short*)region;                    // [4][64*200] (main)
    float* o1L          = (float*)region;                             // [4*576] (post-main)
    unsigned short* XfA = (unsigned short*)(region + 9216);           // [48*200]
    unsigned short* WfA = (unsigned short*)(region + 9216 + 19200);   // [64*200]
    float* yL           = (float*)(region + 54016);                   // [4*576]

    // ---------- helpers ----------
    auto fill_Xf = [&](auto srcf) {   // X'[rr=at*9+m][k'=l(m)*64+c]
        for (int i = t; i < 48 * 192; i += 1024) {
            int rr = i / 192, k = i % 192;
            int lh = k >> 6, c = k & 63;
            float v = 0.f;
            if (rr < 36) {
                int at = rr / 9, m = rr % 9;
                int lm = (m >= 4) ? 2 : (m >= 1 ? 1 : 0);
                if (lh == lm) v = srcf(at, m, c);
            }
            XfA[rr * 200 + k] = f2bf(v);
        }
    };
    auto fill_Wf = [&](const float* wmat) {  // WT[d][k'=l*64+c] = w[l][d][c]
        for (int i = t; i < 64 * 192; i += 1024) {
            int d = i / 192, k = i % 192;
            int lh = k >> 6, c = k & 63;
            WfA[d * 200 + k] = f2bf(wmat[lh * 4096 + d * 64 + c]);
        }
    };
    auto run_linear = [&](const float* bias, float* dst, bool to_global) {
        if (w < 12) {
            int rt = w >> 2, ct = w & 3;
            int row = rt * 16 + (l & 15);
            int col = ct * 16 + (l & 15);
            short8 A[6];
            const unsigned short* ab = XfA + row * 200 + kg * 8;
            #pragma unroll
            for (int kt = 0; kt < 6; ++kt) A[kt] = *(const short8*)(ab + kt * 32);
            const unsigned short* bb = WfA + col * 200 + kg * 8;
            f32x4 acc0 = {0,0,0,0}, acc1 = {0,0,0,0};
            #pragma unroll
            for (int kt = 0; kt < 6; kt += 2) {
                short8 B0 = *(const short8*)(bb + kt * 32);
                short8 B1 = *(const short8*)(bb + (kt + 1) * 32);
                acc0 = __builtin_amdgcn_mfma_f32_16x16x32_bf16(A[kt],     B0, acc0, 0, 0, 0);
                acc1 = __builtin_amdgcn_mfma_f32_16x16x32_bf16(A[kt + 1], B1, acc1, 0, 0, 0);
            }
            f32x4 acc = acc0 + acc1;
            #pragma unroll
            for (int r = 0; r < 4; ++r) {
                int rr = rt * 16 + kg * 4 + r;
                if (rr < 36) {
                    int at = rr / 9, m = rr % 9;
                    float v = acc[r];
                    if (bias && m == 0) v += bias[col];
                    if (to_global) dst[(n0 + at) * 576 + m * 64 + col] = v;
                    else           dst[at * 576 + m * 64 + col] = v;
                }
            }
        }
    };

    // ---------- fc1 ----------
    fill_Xf([&](int at, int m, int c) { return irreps_x[(n0 + at) * 576 + m * 64 + c]; });
    fill_Wf(w_fc1);
    __syncthreads();
    run_linear(b_fc1, xvL, false);
    __syncthreads();

    // ---------- s3 fill: [at][c][k] bf16, stride 200 ----------
    for (int i = t; i < 4 * 64 * 192; i += 1024) {
        int at = i / 12288, r2 = i % 12288, k = r2 / 64, c = r2 % 64;
        int an = atomic_numbers[n0 + at];
        float v = 0.f;
        if (k < 144)      v = xvL[at * 576 + (k >> 4) * 64 + c] * W3[an * 1024 + (k & 15) * 64 + c];
        else if (k < 180) { int j = k - 144;
                            v = xvL[at * 576 + (j >> 2) * 64 + c] * W2[an * 256 + (j & 3) * 64 + c]; }
        s3L[at * 12800 + c * 200 + k] = f2bf(v);
    }
    __syncthreads();

    // ---------- main GEMM: wave = (atom, mtile) ----------
    {
        const int at = w >> 2, mt = w & 3;
        const unsigned short* s3a = s3L + at * 12800;
        short8 A[6];
        {
            int row = mt * 16 + (l & 15);
            const unsigned short* ab = s3a + row * 200 + kg * 8;
            #pragma unroll
            for (int kt = 0; kt < 6; ++kt) A[kt] = *(const short8*)(ab + kt * 32);
        }
        float xw[4];
        {
            int b = l & 15, c0 = mt * 16 + kg * 4;
            #pragma unroll
            for (int r = 0; r < 4; ++r)
                xw[r] = (b < 9) ? xvL[at * 576 + b * 64 + c0 + r] : (b == 9 ? 1.f : 0.f);
        }
        const short8* Bw = (const short8*)U3w;
        for (int nt = 0; nt < 81; ++nt) {
            const short8* Bp = Bw + nt * 64 + l;
            short8 b0 = Bp[0 * 5184], b1 = Bp[1 * 5184], b2 = Bp[2 * 5184],
                   b3 = Bp[3 * 5184], b4 = Bp[4 * 5184], b5 = Bp[5 * 5184];
            f32x4 acc0 = {0,0,0,0}, acc1 = {0,0,0,0};
            acc0 = __builtin_amdgcn_mfma_f32_16x16x32_bf16(A[0], b0, acc0, 0, 0, 0);
            acc1 = __builtin_amdgcn_mfma_f32_16x16x32_bf16(A[1], b1, acc1, 0, 0, 0);
            acc0 = __builtin_amdgcn_mfma_f32_16x16x32_bf16(A[2], b2, acc0, 0, 0, 0);
            acc1 = __builtin_amdgcn_mfma_f32_16x16x32_bf16(A[3], b3, acc1, 0, 0, 0);
            acc0 = __builtin_amdgcn_mfma_f32_16x16x32_bf16(A[4], b4, acc0, 0, 0, 0);
            acc1 = __builtin_amdgcn_mfma_f32_16x16x32_bf16(A[5], b5, acc1, 0, 0, 0);
            float v0 = (acc0[0] + acc1[0]) * xw[0];
            float v1 = (acc0[1] + acc1[1]) * xw[1];
            float v2 = (acc0[2] + acc1[2]) * xw[2];
            float v3 = (acc0[3] + acc1[3]) * xw[3];
            #pragma unroll
            for (int s = 1; s < 16; s <<= 1) {
                v0 += __shfl_xor(v0, s);
                v1 += __shfl_xor(v1, s);
                v2 += __shfl_xor(v2, s);
                v3 += __shfl_xor(v3, s);
            }
            if ((l & 15) == 0) {
                unsigned short* dst = o2L + at * 5184 + nt * 64 + mt * 16 + kg * 4;
                unsigned r01 = (unsigned)f2bf(v0) | ((unsigned)f2bf(v1) << 16);
                unsigned r23 = (unsigned)f2bf(v2) | ((unsigned)f2bf(v3) << 16);
                uint2 pk; pk.x = r01; pk.y = r23;
                *(uint2*)dst = pk;
            }
            if ((nt & 3) == 3) __syncthreads();   // keep 16 waves in one L1 window
        }
    }
    __syncthreads();

    // ---------- out1: sum_a out2[o,a]*x_a + U1 term ----------
    for (int i = t; i < 2304; i += 1024) {
        int at = i / 576, r2 = i % 576, o = r2 >> 6, c = r2 & 63;
        int an = atomic_numbers[n0 + at];
        float w1a = W1[an * 128 + c], w1b = W1[an * 128 + 64 + c];
        const unsigned short* o2p = o2L + at * 5184 + o * 576 + c;
        float acc = 0.f, sa = 0.f, sb = 0.f;
        #pragma unroll
        for (int a = 0; a < 9; ++a)
            acc += bf2f(o2p[a * 64]) * xvL[at * 576 + a * 64 + c];
        #pragma unroll
        for (int i2 = 0; i2 < 9; ++i2) {
            float xc = xvL[at * 576 + i2 * 64 + c];
            sa += U1[o * 18 + i2 * 2]     * xc;
            sb += U1[o * 18 + i2 * 2 + 1] * xc;
        }
        o1L[i] = acc + sa * w1a + sb * w1b;
    }
    __syncthreads();

    // ---------- lin ----------
    fill_Xf([&](int at, int m, int c) { return o1L[at * 576 + m * 64 + c]; });
    fill_Wf(w_lin);
    __syncthreads();
    run_linear(nullptr, yL, false);
    __syncthreads();

    // ---------- fc2 -> global ----------
    fill_Xf([&](int at, int m, int c) { return yL[at * 576 + m * 64 + c]; });
    fill_Wf(w_fc2);
    __syncthreads();
    run_linear(b_fc2, out, true);
}

extern "C" void kernel_launch(void* const* d_in, const int* in_sizes, int n_in,
                              void* d_out, int out_size, void* d_ws, size_t ws_size,
                              hipStream_t stream) {
    const float* irreps_x = (const float*)d_in[0];
    const int*   anum     = (const int*)d_in[1];
    const float* w_fc1    = (const float*)d_in[2];
    const float* b_fc1    = (const float*)d_in[3];
    const float* U3       = (const float*)d_in[4];
    const float* W3       = (const float*)d_in[5];
    const float* U2       = (const float*)d_in[6];
    const float* W2       = (const float*)d_in[7];
    const float* U1       = (const float*)d_in[8];
    const float* W1       = (const float*)d_in[9];
    const float* w_lin    = (const float*)d_in[10];
    const float* w_fc2    = (const float*)d_in[11];
    const float* b_fc2    = (const float*)d_in[12];
    float* out = (float*)d_out;

    unsigned short* U3w = (unsigned short*)d_ws;   // 497664 B needed

    prep_u3w<<<122, 256, 0, stream>>>(U3, U2, U3w);
    mace_main<<<256, 1024, 0, stream>>>(irreps_x, anum, w_fc1, b_fc1, W3, W2,
                                        U1, W1, w_lin, w_fc2, b_fc2, U3w, out);
}

// Round 3
// 122.407 us; speedup vs baseline: 7.4431x; 1.7377x over previous
//
#include <hip/hip_runtime.h>

// MACE body-3, round 3: fold x_b into the A-operand via per-lane fp16 packed
// scaling. Per atom: out2[c][oa] = sum_{b,ip} (s3[c][ip]*xb[c]) * U3[oa][b,ip]
// as one M=64, N=96, K=1344 GEMM in v_mfma_f32_32x32x16_f16.
// Block = 4 atoms, 768 threads = 12 waves = (atom x 3 n-tiles). s3 in regs.

typedef __attribute__((ext_vector_type(8)))  _Float16 f16x8;
typedef __attribute__((ext_vector_type(16))) float    f32x16;
typedef __attribute__((ext_vector_type(4)))  float    f32x4;
typedef __attribute__((ext_vector_type(8)))  short    short8;

static __device__ __forceinline__ unsigned short f2bf(float f) {
    union { float f; unsigned u; } v; v.f = f;
    unsigned r = v.u + 0x7fffu + ((v.u >> 16) & 1u);
    return (unsigned short)(r >> 16);
}

// ---- prep: U3 (+U2 tail) -> fp16 B-fragments for 32x32x16 MFMA ----
// frag idx = (ks*3 + nt)*64 + lane ; lane: col oa = nt*32+(l&31),
// k-elems = 8 f16 at k = ks*16 + (l>>5)*8 + j.  Size 84*3*64*16B = 258048 B.
__global__ void prep_u3w(const float* __restrict__ U3, const float* __restrict__ U2,
                         _Float16* __restrict__ U3w)
{
    int idx = blockIdx.x * 256 + threadIdx.x;   // 63*256 = 16128 exactly
    int ks = idx / 192, r = idx % 192;
    int nt = r >> 6, l = r & 63;
    int oa = nt * 32 + (l & 31), half = l >> 5;
    f16x8 v;
    if (ks < 81) {
        int b = ks / 9, ksub = ks % 9, ip0 = ksub * 16 + half * 8;
        #pragma unroll
        for (int j = 0; j < 8; ++j) {
            float f = (oa < 81) ? U3[(oa * 9 + b) * 144 + ip0 + j] : 0.f;
            v[j] = (_Float16)f;
        }
    } else {
        int ip0 = (ks - 81) * 16 + half * 8;
        #pragma unroll
        for (int j = 0; j < 8; ++j) {
            int ip2 = ip0 + j;
            float f = (oa < 81 && ip2 < 36) ? U2[oa * 36 + ip2] : 0.f;
            v[j] = (_Float16)f;
        }
    }
    ((f16x8*)U3w)[idx] = v;
}

__global__ __launch_bounds__(768, 3) void mace_main(
    const float* __restrict__ irreps_x,
    const int*   __restrict__ atomic_numbers,
    const float* __restrict__ w_fc1,
    const float* __restrict__ b_fc1,
    const float* __restrict__ W3,
    const float* __restrict__ W2,
    const float* __restrict__ U1,
    const float* __restrict__ W1,
    const float* __restrict__ w_lin,
    const float* __restrict__ w_fc2,
    const float* __restrict__ b_fc2,
    const _Float16* __restrict__ U3w,
    float* __restrict__ out)
{
    __shared__ float xvL[2304];                         //  9216 B, [4][9][64]
    __shared__ __align__(16) unsigned char o2B[104448]; // [4][96][68] f32 (main)
    float* const o2L = (float*)o2B;
    // aliases inside o2B for the linear phases:
    float* const o1L          = (float*)o2B;                  // 9216 B
    unsigned short* const XfA = (unsigned short*)(o2B + 9216);  // 48*200*2
    unsigned short* const WfA = (unsigned short*)(o2B + 28416); // 64*200*2
    float* const yL           = (float*)(o2B + 54016);          // 9216 B

    const int t  = threadIdx.x;
    const int n0 = blockIdx.x * 4;
    const int w  = t >> 6;           // 0..11
    const int l  = t & 63;
    const int kg = l >> 4;           // for the 16x16x32 bf16 linears
    const int half = l >> 5;         // for the 32x32x16 f16 main GEMM

    // ---------- so3_linear machinery (bf16 16x16x32, verified in r2) ----------
    auto fill_Xf = [&](auto srcf) {
        for (int i = t; i < 48 * 192; i += 768) {
            int rr = i / 192, k = i % 192;
            int lh = k >> 6, c = k & 63;
            float v = 0.f;
            if (rr < 36) {
                int at = rr / 9, m = rr % 9;
                int lm = (m >= 4) ? 2 : (m >= 1 ? 1 : 0);
                if (lh == lm) v = srcf(at, m, c);
            }
            XfA[rr * 200 + k] = f2bf(v);
        }
    };
    auto fill_Wf = [&](const float* wmat) {
        for (int i = t; i < 64 * 192; i += 768) {
            int d = i / 192, k = i % 192;
            int lh = k >> 6, c = k & 63;
            WfA[d * 200 + k] = f2bf(wmat[lh * 4096 + d * 64 + c]);
        }
    };
    auto run_linear = [&](const float* bias, float* dst, bool to_global) {
        {
            int rt = w >> 2, ct = w & 3;
            int row = rt * 16 + (l & 15);
            int col = ct * 16 + (l & 15);
            short8 A[6];
            const unsigned short* ab = XfA + row * 200 + kg * 8;
            #pragma unroll
            for (int kt = 0; kt < 6; ++kt) A[kt] = *(const short8*)(ab + kt * 32);
            const unsigned short* bb = WfA + col * 200 + kg * 8;
            f32x4 acc0 = {0,0,0,0}, acc1 = {0,0,0,0};
            #pragma unroll
            for (int kt = 0; kt < 6; kt += 2) {
                short8 B0 = *(const short8*)(bb + kt * 32);
                short8 B1 = *(const short8*)(bb + (kt + 1) * 32);
                acc0 = __builtin_amdgcn_mfma_f32_16x16x32_bf16(A[kt],     B0, acc0, 0, 0, 0);
                acc1 = __builtin_amdgcn_mfma_f32_16x16x32_bf16(A[kt + 1], B1, acc1, 0, 0, 0);
            }
            f32x4 acc = acc0 + acc1;
            #pragma unroll
            for (int r = 0; r < 4; ++r) {
                int rr = rt * 16 + kg * 4 + r;
                if (rr < 36) {
                    int at = rr / 9, m = rr % 9;
                    float v = acc[r];
                    if (bias && m == 0) v += bias[col];
                    if (to_global) dst[(n0 + at) * 576 + m * 64 + col] = v;
                    else           dst[at * 576 + m * 64 + col] = v;
                }
            }
        }
    };

    // ---------- fc1 ----------
    fill_Xf([&](int at, int m, int c) { return irreps_x[(n0 + at) * 576 + m * 64 + c]; });
    fill_Wf(w_fc1);
    __syncthreads();
    run_linear(b_fc1, xvL, false);
    __syncthreads();

    // ---------- main GEMM: wave = (atom, n-tile) ----------
    {
        const int at = w / 3, ng = w % 3;
        const int an = atomic_numbers[n0 + at];
        const float* xa  = xvL + at * 576;
        const float* W3r = W3 + an * 1024;
        const float* W2r = W2 + an * 256;

        // s3/s2 fragments in registers (all indices compile-time)
        f16x8 s3f[2][9], s2f[2][3];
        #pragma unroll
        for (int mt = 0; mt < 2; ++mt) {
            const int c = mt * 32 + (l & 31);
            f16x8 w3h;
            #pragma unroll
            for (int j = 0; j < 8; ++j)
                w3h[j] = (_Float16)W3r[(half * 8 + j) * 64 + c];
            #pragma unroll
            for (int i = 0; i < 9; ++i) {
                _Float16 xi = (_Float16)xa[i * 64 + c];
                f16x8 xi8 = {xi, xi, xi, xi, xi, xi, xi, xi};
                s3f[mt][i] = w3h * xi8;
            }
            float w2v[4];
            #pragma unroll
            for (int p = 0; p < 4; ++p) w2v[p] = W2r[p * 64 + c];
            #pragma unroll
            for (int ks2 = 0; ks2 < 3; ++ks2) {
                f16x8 v;
                #pragma unroll
                for (int j = 0; j < 8; ++j) {
                    int ip2 = ks2 * 16 + half * 8 + j;
                    int i = ip2 >> 2;
                    float f = (i < 9) ? xa[i * 64 + c] * w2v[ip2 & 3] : 0.f;
                    v[j] = (_Float16)f;
                }
                s2f[mt][ks2] = v;
            }
        }

        f32x16 acc0 = {0.f}, acc1 = {0.f};
        const f16x8* Bp = (const f16x8*)U3w + ng * 64 + l;
        for (int b = 0; b < 9; ++b) {
            _Float16 h0 = (_Float16)xa[b * 64 + (l & 31)];
            _Float16 h1 = (_Float16)xa[b * 64 + 32 + (l & 31)];
            f16x8 xb0 = {h0, h0, h0, h0, h0, h0, h0, h0};
            f16x8 xb1 = {h1, h1, h1, h1, h1, h1, h1, h1};
            const f16x8* Bb = Bp + b * 9 * 192;
            #pragma unroll
            for (int ksub = 0; ksub < 9; ++ksub) {
                f16x8 B = Bb[ksub * 192];
                acc0 = __builtin_amdgcn_mfma_f32_32x32x16_f16(s3f[0][ksub] * xb0, B, acc0, 0, 0, 0);
                acc1 = __builtin_amdgcn_mfma_f32_32x32x16_f16(s3f[1][ksub] * xb1, B, acc1, 0, 0, 0);
            }
        }
        #pragma unroll
        for (int ks2 = 0; ks2 < 3; ++ks2) {
            f16x8 B = Bp[(81 + ks2) * 192];
            acc0 = __builtin_amdgcn_mfma_f32_32x32x16_f16(s2f[0][ks2], B, acc0, 0, 0, 0);
            acc1 = __builtin_amdgcn_mfma_f32_32x32x16_f16(s2f[1][ks2], B, acc1, 0, 0, 0);
        }

        // epilogue: C/D 32x32 layout col=l&31, row=(reg&3)+8*(reg>>2)+4*(l>>5)
        const int oa = ng * 32 + (l & 31);
        float* o2row = o2L + (at * 96 + oa) * 68;
        #pragma unroll
        for (int q = 0; q < 4; ++q) {
            int c0 = q * 8 + half * 4;
            f32x4 v0 = {acc0[q*4+0], acc0[q*4+1], acc0[q*4+2], acc0[q*4+3]};
            f32x4 v1 = {acc1[q*4+0], acc1[q*4+1], acc1[q*4+2], acc1[q*4+3]};
            *(f32x4*)(o2row + c0)      = v0;
            *(f32x4*)(o2row + 32 + c0) = v1;
        }
    }
    __syncthreads();

    // ---------- out1: sum_a out2[o,a]*x_a + U1 term (into regs first) ----------
    float o1v[3];
    #pragma unroll
    for (int it = 0; it < 3; ++it) {
        int i = t + it * 768;                 // < 2304
        int at2 = i / 576, r2 = i % 576, o = r2 >> 6, c = r2 & 63;
        int an2 = atomic_numbers[n0 + at2];
        float w1a = W1[an2 * 128 + c], w1b = W1[an2 * 128 + 64 + c];
        const float* o2p = o2L + (at2 * 96 + o * 9) * 68 + c;
        float acc = 0.f, sa = 0.f, sb = 0.f;
        #pragma unroll
        for (int a = 0; a < 9; ++a)
            acc += o2p[a * 68] * xvL[at2 * 576 + a * 64 + c];
        #pragma unroll
        for (int i2 = 0; i2 < 9; ++i2) {
            float xc = xvL[at2 * 576 + i2 * 64 + c];
            sa += U1[o * 18 + i2 * 2]     * xc;
            sb += U1[o * 18 + i2 * 2 + 1] * xc;
        }
        o1v[it] = acc + sa * w1a + sb * w1b;
    }
    __syncthreads();
    #pragma unroll
    for (int it = 0; it < 3; ++it) {
        int i = t + it * 768;
        int at2 = i / 576, r2 = i % 576;
        o1L[at2 * 576 + r2] = o1v[it];
    }
    __syncthreads();

    // ---------- lin ----------
    fill_Xf([&](int at, int m, int c) { return o1L[at * 576 + m * 64 + c]; });
    fill_Wf(w_lin);
    __syncthreads();
    run_linear(nullptr, yL, false);
    __syncthreads();

    // ---------- fc2 -> global ----------
    fill_Xf([&](int at, int m, int c) { return yL[at * 576 + m * 64 + c]; });
    fill_Wf(w_fc2);
    __syncthreads();
    run_linear(b_fc2, out, true);
}

extern "C" void kernel_launch(void* const* d_in, const int* in_sizes, int n_in,
                              void* d_out, int out_size, void* d_ws, size_t ws_size,
                              hipStream_t stream) {
    const float* irreps_x = (const float*)d_in[0];
    const int*   anum     = (const int*)d_in[1];
    const float* w_fc1    = (const float*)d_in[2];
    const float* b_fc1    = (const float*)d_in[3];
    const float* U3       = (const float*)d_in[4];
    const float* W3       = (const float*)d_in[5];
    const float* U2       = (const float*)d_in[6];
    const float* W2       = (const float*)d_in[7];
    const float* U1       = (const float*)d_in[8];
    const float* W1       = (const float*)d_in[9];
    const float* w_lin    = (const float*)d_in[10];
    const float* w_fc2    = (const float*)d_in[11];
    const float* b_fc2    = (const float*)d_in[12];
    float* out = (float*)d_out;

    _Float16* U3w = (_Float16*)d_ws;   // 258048 B needed

    prep_u3w<<<63, 256, 0, stream>>>(U3, U2, U3w);
    mace_main<<<256, 768, 0, stream>>>(irreps_x, anum, w_fc1, b_fc1, W3, W2,
                                       U1, W1, w_lin, w_fc2, b_fc2, U3w, out);
}